// Round 8
// baseline (296.240 us; speedup 1.0000x reference)
//
#include <hip/hip_runtime.h>
#include <hip/hip_bf16.h>
#include <math.h>

#define IN_DIM 256
#define NH 4
#define HD 128

typedef __attribute__((ext_vector_type(8))) short short8;
typedef __attribute__((ext_vector_type(4))) float floatx4;
typedef __attribute__((ext_vector_type(2))) float floatx2;

__device__ __forceinline__ unsigned short f2bf(float f) {
    __hip_bfloat16 h = __float2bfloat16(f);
    return *reinterpret_cast<unsigned short*>(&h);
}
__device__ __forceinline__ float asf(unsigned int u) {
    union { unsigned int i; float f; } c; c.i = u; return c.f;
}

// K1 (fully fused): persistent streaming GEMM C[N x 256] = bf16(x) . W^T
//   + exact-fp32 attention logits eattn = exp(x . a2_w^T + a2_b)
//   + CSR rowptr build (grid-strided prologue; done before edge kernel launches)
//   + per-wave direct fp32->bf16 weight conversion (no Wb buffer / prep pass).
// 512 threads = 8 waves; wave w owns cols 32w..32w+31, B-frags in registers.
// SINGLE A-buffer: the two lgkm-barrier structure makes it race-free (all
// MFMA ds_reads of iter i complete before barrier G; phase-A writes of iter
// i+1 occur after G). __launch_bounds__(512, 2): with (512,4) the allocator
// targeted the 64-VGPR tier and spilled ~150 MB/iter (R4 counters:
// FETCH 260 MB vs 105 ideal, MfmaUtil 3.8%).
__global__ __launch_bounds__(512, 2) void node_gemm_k(
    const float* __restrict__ x,
    const float* __restrict__ ll_w, const float* __restrict__ lr_w,
    const float* __restrict__ ll_b, const float* __restrict__ lr_b,
    const float* __restrict__ a2_w, const float* __restrict__ a2_b,
    const int* __restrict__ row, int* __restrict__ rowptr,
    float* __restrict__ eattn,
    unsigned short* __restrict__ xwb, float* __restrict__ out, int N, int E)
{
    __shared__ unsigned short Abuf[32 * 264];     // 16896 B, row stride 528 B
    __shared__ unsigned short LdsX[32 * 136];     //  8704 B
    __shared__ float          LdsO[32 * 132];     // 16896 B  (total 42496 B)

    const int tid = threadIdx.x;
    const int lane = tid & 63;
    const int w = tid >> 6;            // 0..7
    const int lo = lane & 15;
    const int hi = lane >> 4;          // 0..3

    // staging mapping: thread covers row tr, elements tq*4 + 64j + (0..3)
    const int tr = tid >> 4;
    const int tq = tid & 15;

    float4 f0, f1, f2, f3;                    // carried fp32 prefetch (16 VGPRs)
    auto gprefetch = [&](int slab) {
        int rg = slab * 32 + tr;
        if (rg >= N) rg = 0;                  // clamped safe address
        const float* px = x + (size_t)rg * IN_DIM + tq * 4;
        f0 = *(const float4*)(px);
        f1 = *(const float4*)(px + 64);
        f2 = *(const float4*)(px + 128);
        f3 = *(const float4*)(px + 192);
    };

    const int nslab = (N + 31) >> 5;
    int slab = blockIdx.x;
    gprefetch(slab);                          // issue first x loads immediately

    // B fragments: wave w, col-tile ct -> col = 32w + 16ct + lo; direct
    // fp32->bf16 conversion from ll_w/lr_w (2 KB/wave; Wb buffer eliminated).
    short8 Bf[2][8];
    int cols[2]; float bias[2];
    #pragma unroll
    for (int ct = 0; ct < 2; ++ct) {
        const int col = w * 32 + ct * 16 + lo;
        cols[ct] = col;
        bias[ct] = (col < HD) ? ll_b[col] : lr_b[col - HD];
        const float* wsrc = (col < HD) ? (ll_w + (size_t)col * IN_DIM)
                                       : (lr_w + (size_t)(col - HD) * IN_DIM);
        #pragma unroll
        for (int s = 0; s < 8; ++s) {
            const float4 a = *(const float4*)(wsrc + s * 32 + hi * 8);
            const float4 b = *(const float4*)(wsrc + s * 32 + hi * 8 + 4);
            short8 f;
            f[0] = (short)f2bf(a.x); f[1] = (short)f2bf(a.y);
            f[2] = (short)f2bf(a.z); f[3] = (short)f2bf(a.w);
            f[4] = (short)f2bf(b.x); f[5] = (short)f2bf(b.y);
            f[6] = (short)f2bf(b.z); f[7] = (short)f2bf(b.w);
            Bf[ct][s] = f;
        }
    }

    // CSR rowptr build, grid-strided (replaces the separate setup kernel;
    // completes before edge_aggregate_k launches — stream-serialized).
    for (int e = blockIdx.x * 512 + tid; e < E; e += gridDim.x * 512) {
        const int r = row[e];
        const int rprev = (e > 0) ? row[e - 1] : -1;
        for (int rr = rprev + 1; rr <= r; ++rr) rowptr[rr] = e;
        if (e == E - 1) {
            for (int rr = r + 1; rr <= N; ++rr) rowptr[rr] = E;
        }
    }

    const float ab0 = a2_b[0], ab1 = a2_b[1], ab2 = a2_b[2], ab3 = a2_b[3];

    for (; slab < nslab; slab += gridDim.x) {
        unsigned short* ab = &Abuf[0];

        // A: stage — convert prefetched fp32 -> bf16, 4x ds_write_b64
        {
            ushort4 u;
            u.x = f2bf(f0.x); u.y = f2bf(f0.y); u.z = f2bf(f0.z); u.w = f2bf(f0.w);
            *(ushort4*)(ab + tr * 264 + tq * 4) = u;
            u.x = f2bf(f1.x); u.y = f2bf(f1.y); u.z = f2bf(f1.z); u.w = f2bf(f1.w);
            *(ushort4*)(ab + tr * 264 + 64 + tq * 4) = u;
            u.x = f2bf(f2.x); u.y = f2bf(f2.y); u.z = f2bf(f2.z); u.w = f2bf(f2.w);
            *(ushort4*)(ab + tr * 264 + 128 + tq * 4) = u;
            u.x = f2bf(f3.x); u.y = f2bf(f3.y); u.z = f2bf(f3.z); u.w = f2bf(f3.w);
            *(ushort4*)(ab + tr * 264 + 192 + tq * 4) = u;
        }

        // B: attention partial dots (exact fp32) from the same registers;
        //    VALU work fills the ds_write drain window before the barrier
        float p0 = 0.f, p1 = 0.f, p2 = 0.f, p3 = 0.f;
        {
            const float* aw = a2_w + tq * 4;
            #pragma unroll
            for (int j = 0; j < 4; ++j) {
                const float4 fx = (j == 0) ? f0 : (j == 1) ? f1 : (j == 2) ? f2 : f3;
                const float4 w0v = *(const float4*)(aw + 0 * IN_DIM + j * 64);
                const float4 w1v = *(const float4*)(aw + 1 * IN_DIM + j * 64);
                const float4 w2v = *(const float4*)(aw + 2 * IN_DIM + j * 64);
                const float4 w3v = *(const float4*)(aw + 3 * IN_DIM + j * 64);
                p0 += fx.x * w0v.x + fx.y * w0v.y + fx.z * w0v.z + fx.w * w0v.w;
                p1 += fx.x * w1v.x + fx.y * w1v.y + fx.z * w1v.z + fx.w * w1v.w;
                p2 += fx.x * w2v.x + fx.y * w2v.y + fx.z * w2v.z + fx.w * w2v.w;
                p3 += fx.x * w3v.x + fx.y * w3v.y + fx.z * w3v.z + fx.w * w3v.w;
            }
        }

        // C: LDS-visibility barrier (lgkm only; vm prefetch/stores untouched)
        asm volatile("s_waitcnt lgkmcnt(0)\n\ts_barrier" ::: "memory");

        // D: prefetch next slab FIRST — loads go in flight under the MFMA loop
        //    (f0..f3 are dead after phase B)
        const int next = slab + gridDim.x;
        if (next < nslab) gprefetch(next);

        floatx4 acc[2][2];
        #pragma unroll
        for (int rt = 0; rt < 2; ++rt)
            #pragma unroll
            for (int ct = 0; ct < 2; ++ct)
                acc[rt][ct] = (floatx4){0.f, 0.f, 0.f, 0.f};

        #pragma unroll
        for (int s = 0; s < 8; ++s) {
            const short8 A0 = *(const short8*)(ab + lo * 264 + s * 32 + hi * 8);
            const short8 A1 = *(const short8*)(ab + (16 + lo) * 264 + s * 32 + hi * 8);
            acc[0][0] = __builtin_amdgcn_mfma_f32_16x16x32_bf16(A0, Bf[0][s], acc[0][0], 0, 0, 0);
            acc[0][1] = __builtin_amdgcn_mfma_f32_16x16x32_bf16(A0, Bf[1][s], acc[0][1], 0, 0, 0);
            acc[1][0] = __builtin_amdgcn_mfma_f32_16x16x32_bf16(A1, Bf[0][s], acc[1][0], 0, 0, 0);
            acc[1][1] = __builtin_amdgcn_mfma_f32_16x16x32_bf16(A1, Bf[1][s], acc[1][1], 0, 0, 0);
        }

        // E: reduce attn over the 16 staging lanes of this row, store eattn
        //    (after MFMA issue so the shuffle/exp chain overlaps matrix work)
        #pragma unroll
        for (int o = 1; o < 16; o <<= 1) {
            p0 += __shfl_xor(p0, o, 64);
            p1 += __shfl_xor(p1, o, 64);
            p2 += __shfl_xor(p2, o, 64);
            p3 += __shfl_xor(p3, o, 64);
        }
        {
            const int rgo = slab * 32 + tr;
            if (tq == 0 && rgo < N) {
                float4 ev;
                ev.x = __expf(p0 + ab0);
                ev.y = __expf(p1 + ab1);
                ev.z = __expf(p2 + ab2);
                ev.w = __expf(p3 + ab3);
                *(float4*)(eattn + (size_t)rgo * NH) = ev;
            }
        }

        // F: accumulators -> epilogue LDS (C/D layout: col = lo, row = 4hi + reg)
        #pragma unroll
        for (int rt = 0; rt < 2; ++rt)
            #pragma unroll
            for (int ct = 0; ct < 2; ++ct) {
                const int c = cols[ct];
                #pragma unroll
                for (int j = 0; j < 4; ++j) {
                    const int r = rt * 16 + hi * 4 + j;
                    const float v = acc[rt][ct][j] + bias[ct];
                    if (c < HD) LdsX[r * 136 + c] = f2bf(v);
                    else        LdsO[r * 132 + (c - HD)] = v;
                }
            }

        // G: epilogue barrier, lgkm only (prefetch stays in flight)
        asm volatile("s_waitcnt lgkmcnt(0)\n\ts_barrier" ::: "memory");

        // H: coalesced stores from epilogue LDS
        {
            const int rg = slab * 32 + tr;
            if (rg < N) {
                *(uint4*)(xwb + (size_t)rg * HD + tq * 8) =
                    *(const uint4*)(LdsX + tr * 136 + tq * 8);
                float4* od = (float4*)(out + (size_t)rg * HD + tq * 8);
                const float* lsrc = LdsO + tr * 132 + tq * 8;
                od[0] = *(const float4*)(lsrc);
                od[1] = *(const float4*)(lsrc + 4);
            }
        }
    }
}

// K2: single-pass fused softmax + aggregation. One wave per destination node.
// 8-wide gather pipeline (R5 variant — best measured, 82.8 µs). R5-R7
// established this kernel is at its L2-fill throughput roofline (~3.9 TB/s
// across VGPR 16/20/32 ILP variants; dur tracks bytes linearly): compulsory
// gather bytes E*(256+16) + out RMW ~= 540 MB at the observed service rate.
__global__ __launch_bounds__(256) void edge_aggregate_k(
    const int* __restrict__ rowptr, const int* __restrict__ col,
    const float* __restrict__ eattn,
    const unsigned short* __restrict__ xwb, float* __restrict__ out,
    int N, int E)
{
    const int n = blockIdx.x * 4 + (threadIdx.x >> 6);
    const int lane = threadIdx.x & 63;
    if (n >= N) return;
    const int e0 = __builtin_amdgcn_readfirstlane(rowptr[n]);
    const int e1 = __builtin_amdgcn_readfirstlane(rowptr[n + 1]);
    if (e0 >= e1) return;   // isolated node: out keeps lin_r base

    const int h = lane >> 4;          // head of dims 2*lane, 2*lane+1
    const int d2 = 2 * lane;
    const int elast = E - 1;

    auto cl = [&](int i) { return col[i <= elast ? i : elast]; };

    // out RMW load issued early; non-temporal so this one-shot stream doesn't
    // evict the xwb gather table from L2
    floatx2* op = (floatx2*)(out + (size_t)n * HD + d2);
    floatx2 o = __builtin_nontemporal_load(op);

    float s = 0.f, acc0 = 0.f, acc1 = 0.f;
    int e = e0;
    int c[8];
    #pragma unroll
    for (int i = 0; i < 8; ++i) c[i] = cl(e + i);

    for (;;) {
        // 16 independent gathers for the current group (indices always valid)
        float wt[8];
        unsigned int pk[8];
        #pragma unroll
        for (int i = 0; i < 8; ++i) wt[i] = eattn[c[i] * NH + h];
        #pragma unroll
        for (int i = 0; i < 8; ++i)
            pk[i] = *(const unsigned int*)(xwb + (size_t)c[i] * HD + d2);
        // next group's indices load while the gathers are in flight
        const int ne = e + 8;
        int nx[8];
        #pragma unroll
        for (int i = 0; i < 8; ++i) nx[i] = cl(ne + i);
        // mask out-of-range edges (wave-uniform conditions -> cndmask)
        #pragma unroll
        for (int i = 1; i < 8; ++i) wt[i] = (e + i < e1) ? wt[i] : 0.f;
        #pragma unroll
        for (int i = 0; i < 8; ++i) {
            s += wt[i];
            acc0 += wt[i] * asf(pk[i] << 16);
            acc1 += wt[i] * asf(pk[i] & 0xffff0000u);
        }
        if (ne >= e1) break;
        e = ne;
        #pragma unroll
        for (int i = 0; i < 8; ++i) c[i] = nx[i];
    }

    const float inv = 1.f / s;
    o.x += acc0 * inv;
    o.y += acc1 * inv;
    __builtin_nontemporal_store(o, op);
}

extern "C" void kernel_launch(void* const* d_in, const int* in_sizes, int n_in,
                              void* d_out, int out_size, void* d_ws, size_t ws_size,
                              hipStream_t stream) {
    const float* x    = (const float*)d_in[0];
    const int*   row  = (const int*)d_in[1];
    const int*   col  = (const int*)d_in[2];
    const float* a2_w = (const float*)d_in[5];
    const float* a2_b = (const float*)d_in[6];
    const float* ll_w = (const float*)d_in[7];
    const float* ll_b = (const float*)d_in[8];
    const float* lr_w = (const float*)d_in[9];
    const float* lr_b = (const float*)d_in[10];
    float* out = (float*)d_out;

    const int N = in_sizes[0] / IN_DIM;
    const int E = in_sizes[1];

    // ws layout: rowptr | eattn | xwb (bf16)   (~27 MB)
    char* ws = (char*)d_ws;
    size_t off = ((size_t)(N + 1) * sizeof(int) + 255) & ~(size_t)255;
    int*   rowptr = (int*)ws;
    float* eattn  = (float*)(ws + off); off += (size_t)N * NH * sizeof(float);
    unsigned short* xwb = (unsigned short*)(ws + off); off += (size_t)N * HD * sizeof(unsigned short);

    node_gemm_k<<<768, 512, 0, stream>>>(x, ll_w, lr_w, ll_b, lr_b, a2_w, a2_b,
                                         row, rowptr, eattn, xwb, out, N, E);
    edge_aggregate_k<<<(N + 3) / 4, 256, 0, stream>>>(rowptr, col, eattn, xwb, out, N, E);
}

// Round 9
// 278.606 us; speedup vs baseline: 1.0633x; 1.0633x over previous
//
#include <hip/hip_runtime.h>
#include <hip/hip_bf16.h>
#include <math.h>

#define IN_DIM 256
#define NH 4
#define HD 128

typedef __attribute__((ext_vector_type(8))) short short8;
typedef __attribute__((ext_vector_type(4))) float floatx4;
typedef __attribute__((ext_vector_type(2))) float floatx2;

__device__ __forceinline__ unsigned short f2bf(float f) {
    __hip_bfloat16 h = __float2bfloat16(f);
    return *reinterpret_cast<unsigned short*>(&h);
}
__device__ __forceinline__ float asf(unsigned int u) {
    union { unsigned int i; float f; } c; c.i = u; return c.f;
}

// K0 (setup): blocks 0..255 convert [ll_w; lr_w] -> Wb (bf16 [col][k]);
// blocks 256.. build CSR row pointers from sorted row[].
__global__ __launch_bounds__(256) void setup_k(const float* __restrict__ ll_w,
                                               const float* __restrict__ lr_w,
                                               unsigned short* __restrict__ Wb,
                                               const int* __restrict__ row,
                                               int* __restrict__ rowptr,
                                               int E, int N) {
    if (blockIdx.x < 256) {
        int idx = blockIdx.x * 256 + threadIdx.x;
        int j = idx >> 8, k = idx & 255;
        float v = (j < 128) ? ll_w[(size_t)j * 256 + k] : lr_w[(size_t)(j - 128) * 256 + k];
        Wb[idx] = f2bf(v);
        return;
    }
    int e = (blockIdx.x - 256) * blockDim.x + threadIdx.x;
    if (e >= E) return;
    int r = row[e];
    int rprev = (e > 0) ? row[e - 1] : -1;
    for (int rr = rprev + 1; rr <= r; ++rr) rowptr[rr] = e;
    if (e == E - 1) {
        for (int rr = r + 1; rr <= N; ++rr) rowptr[rr] = E;
    }
}

// K1: persistent streaming GEMM xwb[N x 256](bf16) = bf16(x) . Wb^T + bias
//     + exact-fp32 attention logits eattn = exp(x . a2_w^T + a2_b).
// cols 0..127 = lin_l (gathered by edge kernel); cols 128..255 = lin_r
// (read back row-wise by edge kernel; `out` is written ONLY by edge —
// removes the 51 MB fp32 out write + 51 MB RMW re-read of R6).
// R6-proven skeleton: grid 512 (exactly 2 blocks/CU resident, no tail),
// Wb-based B-frags, no prologue work (R8's fused prologue + grid-768 tail
// cost ~20 µs). __launch_bounds__(512,2): (512,4) made the allocator target
// the 64-VGPR tier and spill ~150 MB/iter (R4).
__global__ __launch_bounds__(512, 2) void node_gemm_k(
    const float* __restrict__ x, const unsigned short* __restrict__ Wb,
    const float* __restrict__ ll_b, const float* __restrict__ lr_b,
    const float* __restrict__ a2_w, const float* __restrict__ a2_b,
    float* __restrict__ eattn,
    unsigned short* __restrict__ xwb, int N)
{
    __shared__ unsigned short Abuf[32 * 264];   // 16896 B, row stride 528 B
    __shared__ unsigned short LdsE[32 * 264];   // 16896 B, unified bf16 epilogue

    const int tid = threadIdx.x;
    const int lane = tid & 63;
    const int w = tid >> 6;            // 0..7
    const int lo = lane & 15;
    const int hi = lane >> 4;          // 0..3

    // B fragments in registers: wave w, col-tile ct -> col = 32w + 16ct + lo.
    short8 Bf[2][8];
    int cols[2]; float bias[2];
    #pragma unroll
    for (int ct = 0; ct < 2; ++ct) {
        const int col = w * 32 + ct * 16 + lo;
        cols[ct] = col;
        bias[ct] = (col < HD) ? ll_b[col] : lr_b[col - HD];
        #pragma unroll
        for (int s = 0; s < 8; ++s)
            Bf[ct][s] = *(const short8*)(Wb + (size_t)col * IN_DIM + s * 32 + hi * 8);
    }

    // staging mapping: thread covers row tr, elements tq*4 + 64j + (0..3)
    const int tr = tid >> 4;
    const int tq = tid & 15;

    const float ab0 = a2_b[0], ab1 = a2_b[1], ab2 = a2_b[2], ab3 = a2_b[3];

    float4 f0, f1, f2, f3;                    // carried fp32 prefetch (16 VGPRs)
    auto gprefetch = [&](int slab) {
        int rg = slab * 32 + tr;
        if (rg >= N) rg = 0;                  // clamped safe address
        const float* px = x + (size_t)rg * IN_DIM + tq * 4;
        f0 = *(const float4*)(px);
        f1 = *(const float4*)(px + 64);
        f2 = *(const float4*)(px + 128);
        f3 = *(const float4*)(px + 192);
    };

    const int nslab = (N + 31) >> 5;
    int slab = blockIdx.x;
    gprefetch(slab);

    for (; slab < nslab; slab += gridDim.x) {
        unsigned short* ab = &Abuf[0];

        // A: stage — convert prefetched fp32 -> bf16, 4x ds_write_b64
        {
            ushort4 u;
            u.x = f2bf(f0.x); u.y = f2bf(f0.y); u.z = f2bf(f0.z); u.w = f2bf(f0.w);
            *(ushort4*)(ab + tr * 264 + tq * 4) = u;
            u.x = f2bf(f1.x); u.y = f2bf(f1.y); u.z = f2bf(f1.z); u.w = f2bf(f1.w);
            *(ushort4*)(ab + tr * 264 + 64 + tq * 4) = u;
            u.x = f2bf(f2.x); u.y = f2bf(f2.y); u.z = f2bf(f2.z); u.w = f2bf(f2.w);
            *(ushort4*)(ab + tr * 264 + 128 + tq * 4) = u;
            u.x = f2bf(f3.x); u.y = f2bf(f3.y); u.z = f2bf(f3.z); u.w = f2bf(f3.w);
            *(ushort4*)(ab + tr * 264 + 192 + tq * 4) = u;
        }

        // B: attention partial dots (exact fp32) from the same registers;
        //    VALU work fills the ds_write drain window before the barrier
        float p0 = 0.f, p1 = 0.f, p2 = 0.f, p3 = 0.f;
        {
            const float* aw = a2_w + tq * 4;
            #pragma unroll
            for (int j = 0; j < 4; ++j) {
                const float4 fx = (j == 0) ? f0 : (j == 1) ? f1 : (j == 2) ? f2 : f3;
                const float4 w0v = *(const float4*)(aw + 0 * IN_DIM + j * 64);
                const float4 w1v = *(const float4*)(aw + 1 * IN_DIM + j * 64);
                const float4 w2v = *(const float4*)(aw + 2 * IN_DIM + j * 64);
                const float4 w3v = *(const float4*)(aw + 3 * IN_DIM + j * 64);
                p0 += fx.x * w0v.x + fx.y * w0v.y + fx.z * w0v.z + fx.w * w0v.w;
                p1 += fx.x * w1v.x + fx.y * w1v.y + fx.z * w1v.z + fx.w * w1v.w;
                p2 += fx.x * w2v.x + fx.y * w2v.y + fx.z * w2v.z + fx.w * w2v.w;
                p3 += fx.x * w3v.x + fx.y * w3v.y + fx.z * w3v.z + fx.w * w3v.w;
            }
        }

        // C: LDS-visibility barrier (lgkm only; vm prefetch/stores untouched)
        asm volatile("s_waitcnt lgkmcnt(0)\n\ts_barrier" ::: "memory");

        // D: prefetch next slab FIRST — loads go in flight under the shuffle
        //    chain and the MFMA loop (f0..f3 are dead after phase B)
        const int next = slab + gridDim.x;
        if (next < nslab) gprefetch(next);

        // E: reduce attn over the 16 staging lanes of this row, store eattn
        #pragma unroll
        for (int o = 1; o < 16; o <<= 1) {
            p0 += __shfl_xor(p0, o, 64);
            p1 += __shfl_xor(p1, o, 64);
            p2 += __shfl_xor(p2, o, 64);
            p3 += __shfl_xor(p3, o, 64);
        }
        {
            const int rgo = slab * 32 + tr;
            if (tq == 0 && rgo < N) {
                float4 ev;
                ev.x = __expf(p0 + ab0);
                ev.y = __expf(p1 + ab1);
                ev.z = __expf(p2 + ab2);
                ev.w = __expf(p3 + ab3);
                *(float4*)(eattn + (size_t)rgo * NH) = ev;
            }
        }

        floatx4 acc[2][2];
        #pragma unroll
        for (int rt = 0; rt < 2; ++rt)
            #pragma unroll
            for (int ct = 0; ct < 2; ++ct)
                acc[rt][ct] = (floatx4){0.f, 0.f, 0.f, 0.f};

        #pragma unroll
        for (int s = 0; s < 8; ++s) {
            const short8 A0 = *(const short8*)(ab + lo * 264 + s * 32 + hi * 8);
            const short8 A1 = *(const short8*)(ab + (16 + lo) * 264 + s * 32 + hi * 8);
            acc[0][0] = __builtin_amdgcn_mfma_f32_16x16x32_bf16(A0, Bf[0][s], acc[0][0], 0, 0, 0);
            acc[0][1] = __builtin_amdgcn_mfma_f32_16x16x32_bf16(A0, Bf[1][s], acc[0][1], 0, 0, 0);
            acc[1][0] = __builtin_amdgcn_mfma_f32_16x16x32_bf16(A1, Bf[0][s], acc[1][0], 0, 0, 0);
            acc[1][1] = __builtin_amdgcn_mfma_f32_16x16x32_bf16(A1, Bf[1][s], acc[1][1], 0, 0, 0);
        }

        // F: accumulators -> unified bf16 epilogue LDS
        //    (C/D layout: col = lo, row = 4hi + reg)
        #pragma unroll
        for (int rt = 0; rt < 2; ++rt)
            #pragma unroll
            for (int ct = 0; ct < 2; ++ct) {
                const int c = cols[ct];
                #pragma unroll
                for (int j = 0; j < 4; ++j) {
                    const int r = rt * 16 + hi * 4 + j;
                    LdsE[r * 264 + c] = f2bf(acc[rt][ct][j] + bias[ct]);
                }
            }

        // G: epilogue barrier, lgkm only (prefetch stays in flight)
        asm volatile("s_waitcnt lgkmcnt(0)\n\ts_barrier" ::: "memory");

        // H: coalesced stores — 32 B per thread, one full 256-col bf16 row set
        {
            const int rg = slab * 32 + tr;
            if (rg < N) {
                const uint4* lsrc = (const uint4*)(LdsE + tr * 264 + tq * 16);
                uint4* dst = (uint4*)(xwb + (size_t)rg * 256 + tq * 16);
                dst[0] = lsrc[0];
                dst[1] = lsrc[1];
            }
        }
    }
}

// K2: single-pass fused softmax + aggregation + lin_r add. One wave per
// destination node. 8-wide gather pipeline (best of R5-R7; this kernel is at
// its gather-throughput roofline ~3.9 TB/s across ILP depths 4/8/16).
// Changes vs R6: gathers at stride 256 (unified xwb), lin_r read as a
// coalesced bf16 row (25.6 MB) instead of a 51 MB fp32 out RMW-load, and
// `out` becomes a pure non-temporal store.
__global__ __launch_bounds__(256) void edge_aggregate_k(
    const int* __restrict__ rowptr, const int* __restrict__ col,
    const float* __restrict__ eattn,
    const unsigned short* __restrict__ xwb, float* __restrict__ out,
    int N, int E)
{
    const int n = blockIdx.x * 4 + (threadIdx.x >> 6);
    const int lane = threadIdx.x & 63;
    if (n >= N) return;
    const int e0 = __builtin_amdgcn_readfirstlane(rowptr[n]);
    const int e1 = __builtin_amdgcn_readfirstlane(rowptr[n + 1]);

    const int h = lane >> 4;          // head of dims 2*lane, 2*lane+1
    const int d2 = 2 * lane;
    const int elast = E - 1;

    auto cl = [&](int i) { return col[i <= elast ? i : elast]; };

    // lin_r contribution for this node: coalesced bf16 row read (issued early)
    const unsigned int lr = *(const unsigned int*)(xwb + (size_t)n * 256 + HD + d2);
    const float lrx = asf(lr << 16);
    const float lry = asf(lr & 0xffff0000u);

    float2 o;
    o.x = lrx; o.y = lry;

    if (e0 < e1) {
        float s = 0.f, acc0 = 0.f, acc1 = 0.f;
        int e = e0;
        int c[8];
        #pragma unroll
        for (int i = 0; i < 8; ++i) c[i] = cl(e + i);

        for (;;) {
            // 16 independent gathers for the current group (indices always valid)
            float wt[8];
            unsigned int pk[8];
            #pragma unroll
            for (int i = 0; i < 8; ++i) wt[i] = eattn[c[i] * NH + h];
            #pragma unroll
            for (int i = 0; i < 8; ++i)
                pk[i] = *(const unsigned int*)(xwb + (size_t)c[i] * 256 + d2);
            // next group's indices load while the gathers are in flight
            const int ne = e + 8;
            int nx[8];
            #pragma unroll
            for (int i = 0; i < 8; ++i) nx[i] = cl(ne + i);
            // mask out-of-range edges (wave-uniform conditions -> cndmask)
            #pragma unroll
            for (int i = 1; i < 8; ++i) wt[i] = (e + i < e1) ? wt[i] : 0.f;
            #pragma unroll
            for (int i = 0; i < 8; ++i) {
                s += wt[i];
                acc0 += wt[i] * asf(pk[i] << 16);
                acc1 += wt[i] * asf(pk[i] & 0xffff0000u);
            }
            if (ne >= e1) break;
            e = ne;
            #pragma unroll
            for (int i = 0; i < 8; ++i) c[i] = nx[i];
        }

        const float inv = 1.f / s;
        o.x += acc0 * inv;
        o.y += acc1 * inv;
    }

    floatx2* op = (floatx2*)(out + (size_t)n * HD + d2);
    floatx2 ov;
    ov.x = o.x; ov.y = o.y;
    __builtin_nontemporal_store(ov, op);
}

extern "C" void kernel_launch(void* const* d_in, const int* in_sizes, int n_in,
                              void* d_out, int out_size, void* d_ws, size_t ws_size,
                              hipStream_t stream) {
    const float* x    = (const float*)d_in[0];
    const int*   row  = (const int*)d_in[1];
    const int*   col  = (const int*)d_in[2];
    const float* a2_w = (const float*)d_in[5];
    const float* a2_b = (const float*)d_in[6];
    const float* ll_w = (const float*)d_in[7];
    const float* ll_b = (const float*)d_in[8];
    const float* lr_w = (const float*)d_in[9];
    const float* lr_b = (const float*)d_in[10];
    float* out = (float*)d_out;

    const int N = in_sizes[0] / IN_DIM;
    const int E = in_sizes[1];

    // ws layout: rowptr | eattn | xwb (bf16, N x 256) | Wb (bf16)  (~53 MB)
    char* ws = (char*)d_ws;
    size_t off = ((size_t)(N + 1) * sizeof(int) + 255) & ~(size_t)255;
    int*   rowptr = (int*)ws;
    float* eattn  = (float*)(ws + off); off += (size_t)N * NH * sizeof(float);
    unsigned short* xwb = (unsigned short*)(ws + off); off += (size_t)N * 256 * sizeof(unsigned short);
    unsigned short* Wb  = (unsigned short*)(ws + off); off += (size_t)256 * IN_DIM * sizeof(unsigned short);

    setup_k<<<256 + (E + 255) / 256, 256, 0, stream>>>(ll_w, lr_w, Wb, row, rowptr, E, N);
    node_gemm_k<<<512, 512, 0, stream>>>(x, Wb, ll_b, lr_b, a2_w, a2_b, eattn, xwb, N);
    edge_aggregate_k<<<(N + 3) / 4, 256, 0, stream>>>(rowptr, col, eattn, xwb, out, N, E);
}